// Round 10
// baseline (366.535 us; speedup 1.0000x reference)
//
#include <hip/hip_runtime.h>
#include <hip/hip_bf16.h>
#include <stdint.h>

#define LOG2E 1.44269504088896340736f
#define LN2   0.69314718055994530942f

typedef __attribute__((ext_vector_type(8))) __bf16 bf16x8;
typedef __attribute__((ext_vector_type(4))) float  f32x4;

static constexpr int B = 128, S = 512, T = 256;
static constexpr int LDP = T + 8;   // padded LDS row (bf16 elems)
static constexpr int H   = 256;     // forward covers s=1..H, backward s=S-1..H+1
static constexpr int NSF = H;           // 256 forward steps
static constexpr int NSB = S - 1 - H;   // 255 backward steps
static constexpr int NWG = 32;          // 2 scans x 2 dirs x 8 batch-groups

static __device__ __forceinline__ uint pack_bf16x2(float a, float b) {
    __hip_bfloat162 h = __float22bfloat162_rn(make_float2(a, b));
    union { __hip_bfloat162 h; uint u; } cv; cv.h = h;
    return cv.u;
}
static __device__ __forceinline__ float bf2f(ushort u) {
    return __uint_as_float(((uint)u) << 16);
}

// lgkm-only barrier: LDS writes must be visible, but leave global loads in
// flight (no vmcnt drain).  sched_barrier stops motion across it (rule #18).
static __device__ __forceinline__ void wg_barrier() {
    asm volatile("s_waitcnt lgkmcnt(0)" ::: "memory");
    __builtin_amdgcn_s_barrier();
    __builtin_amdgcn_sched_barrier(0);
}

// fmax over the 2x4 epilogue tile in a FIXED order so the tracking path and
// the rn-only path produce bitwise-equal maxima.
static __device__ __forceinline__ float vmax24(const float v[2][4]) {
    float m = 0.0f;
    #pragma unroll
    for (int t = 0; t < 2; ++t)
        #pragma unroll
        for (int r = 0; r < 4; ++r) m = fmaxf(m, v[t][r]);
    return m;
}

// ---- prep: Et[j][i] = bf16(exp(trans[i][j])), Em[i][j] = bf16(exp(trans[i][j]))
//      also resets the last-WG-done counter for this iteration (stream-ordered
//      before crf_scan, so no race).
__global__ void prep_mats(const float* __restrict__ trans,
                          ushort* __restrict__ Et, ushort* __restrict__ Em,
                          int* __restrict__ cnt) {
    int i = blockIdx.x;    // 256 (row of trans)
    int j = threadIdx.x;   // 256
    if (i == 0 && j == 0) *cnt = 0;
    float e = exp2f(trans[i * T + j] * LOG2E);
    uint u = __float_as_uint(e);
    ushort h = (ushort)((u + 0x7FFFu + ((u >> 16) & 1u)) >> 16);  // RTNE
    Em[i * T + j] = h;     // exp(trans) row-major   (backward A-operand)
    Et[j * T + i] = h;     // exp(trans) transposed  (forward  A-operand)
}

// ---- scan body: 8 waves per WG (512 thr), wave w owns j in [32w, 32w+32).
// Measured-best structure (1.02 us/step): straight k-tile order, 2-way
// accumulator split, lgkm-only barrier, em read as f32 with one-group-ahead
// prefetch and exp2f computed before the MFMA block (rides in pipe shadows).
template<int DIR>
static __device__ __forceinline__ void scan_body(
    const float* __restrict__ em,
    const int* __restrict__ mask, const float* __restrict__ startt,
    const float* __restrict__ endt, const ushort* __restrict__ Amat,
    float* __restrict__ vecbuf, int* __restrict__ lsbuf,
    const int scan, const int bg,
    ushort (&Al)[2][16][LDP], float (&mx2)[16][8])
{
    constexpr int NSTEP = DIR ? NSB : NSF;
    constexpr int PGRP  = (NSTEP + 3) / 4;

    const int tid  = threadIdx.x;
    const int w    = tid >> 6;          // wave 0..7
    const int lane = tid & 63;
    const int q    = lane >> 4;         // quad 0..3
    const int l    = lane & 15;         // local batch 0..15
    const int b    = bg * 16 + l;

    // step idx -> em row (epilogue) / mask row (the where())
    #define EROW(ix) (DIR ? (S - 2 - (ix)) : (1 + (ix)))
    #define MROW(ix) (DIR ? (S - 1 - (ix)) : (1 + (ix)))

    // ---- A fragments (step-invariant): 64 VGPRs/wave
    bf16x8 Afr[2][8];
    #pragma unroll
    for (int t = 0; t < 2; ++t) {
        int j = w * 32 + t * 16 + l;
        #pragma unroll
        for (int kt = 0; kt < 8; ++kt)
            Afr[t][kt] = *reinterpret_cast<const bf16x8*>(&Amat[j * T + kt * 32 + q * 8]);
    }

    const float* emrow = em  + (size_t)b * S * T;
    const int*   mrow  = mask + (size_t)b * S;

    int ls = 0;
    int buf = 0;
    float areg[2][4];   // DIR=1: raw beta (pre-em), scaled. DIR=0: unused.

    // ---- init
    {
        const int    r0 = DIR ? (S - 1) : 0;
        const float* tv = DIR ? endt : startt;
        float v0[2][4], gg[2][4]; float mx = 0.0f;
        #pragma unroll
        for (int t = 0; t < 2; ++t) {
            int j0 = w * 32 + t * 16 + q * 4;
            f32x4 e4 = *reinterpret_cast<const f32x4*>(&emrow[(size_t)r0 * T + j0]);
            f32x4 s4 = *reinterpret_cast<const f32x4*>(&tv[j0]);
            #pragma unroll
            for (int r = 0; r < 4; ++r) {
                float full = exp2f((e4[r] + s4[r]) * LOG2E);
                v0[t][r] = full;
                gg[t][r] = DIR ? exp2f(s4[r] * LOG2E) : full;
                mx = fmaxf(mx, full);
            }
        }
        mx = fmaxf(mx, __shfl_xor(mx, 16));
        mx = fmaxf(mx, __shfl_xor(mx, 32));
        if (q == 0) mx2[l][w] = mx;
        __syncthreads();
        f32x4 ma = *reinterpret_cast<const f32x4*>(&mx2[l][0]);
        f32x4 mb = *reinterpret_cast<const f32x4*>(&mx2[l][4]);
        float gmx = fmaxf(fmaxf(fmaxf(ma[0], ma[1]), fmaxf(ma[2], ma[3])),
                          fmaxf(fmaxf(mb[0], mb[1]), fmaxf(mb[2], mb[3])));
        int e = (int)((__float_as_uint(gmx) >> 23) & 255u) - 127;
        float sc = __uint_as_float((uint)(127 - e) << 23);   // exact 2^-e
        ls = e;
        #pragma unroll
        for (int t = 0; t < 2; ++t) {
            int j0 = w * 32 + t * 16 + q * 4;
            uint2 wv;
            wv.x = pack_bf16x2(v0[t][0] * sc, v0[t][1] * sc);
            wv.y = pack_bf16x2(v0[t][2] * sc, v0[t][3] * sc);
            *reinterpret_cast<uint2*>(&Al[0][l][j0]) = wv;
            if (DIR) {
                #pragma unroll
                for (int r = 0; r < 4; ++r) areg[t][r] = gg[t][r] * sc;
            }
        }
        __syncthreads();
        if (q == 0) mx2[l][w] = mx * sc;
        __syncthreads();
    }

    // full per-step max tracking only needed when the stored vector can
    // persist across a masked step: forward score chain only.
    const bool track = (DIR == 0) && (scan != 0);

    // ---- preload em/mask for group 0 (idx 0..3), f32
    f32x4 exv[4][2]; int mks[4];
    #pragma unroll
    for (int u = 0; u < 4; ++u) {
        int iu = u < NSTEP ? u : NSTEP - 1;
        #pragma unroll
        for (int t = 0; t < 2; ++t) {
            int j0 = w * 32 + t * 16 + q * 4;
            exv[u][t] = *reinterpret_cast<const f32x4*>(&emrow[(size_t)EROW(iu) * T + j0]);
        }
        mks[u] = (scan && u < NSTEP) ? mrow[MROW(iu)] : 1;
    }

    for (int p = 0; p < PGRP; ++p) {
        // ---- issue next group's loads now (stay in flight across barriers)
        f32x4 exn[4][2]; int mkn[4];
        #pragma unroll
        for (int u = 0; u < 4; ++u) {
            int idx  = 4 * (p + 1) + u;
            int idxc = idx < NSTEP ? idx : NSTEP - 1;
            #pragma unroll
            for (int t = 0; t < 2; ++t) {
                int j0 = w * 32 + t * 16 + q * 4;
                exn[u][t] = *reinterpret_cast<const f32x4*>(&emrow[(size_t)EROW(idxc) * T + j0]);
            }
            mkn[u] = (scan && idx < NSTEP) ? mrow[MROW(idxc)] : 1;
        }

        float pend = 1.0f, vml = 0.0f; int pk = 0;

        #pragma unroll
        for (int u = 0; u < 4; ++u) {
            const int idx = 4 * p + u;
            if (idx < NSTEP) {
                if (u == 0) {   // renorm-group start: derive kappa
                    f32x4 ma = *reinterpret_cast<const f32x4*>(&mx2[l][0]);
                    f32x4 mb = *reinterpret_cast<const f32x4*>(&mx2[l][4]);
                    float gmx = fmaxf(fmaxf(fmaxf(ma[0], ma[1]), fmaxf(ma[2], ma[3])),
                                      fmaxf(fmaxf(mb[0], mb[1]), fmaxf(mb[2], mb[3])));
                    int kap = (int)((__float_as_uint(gmx) >> 23) & 255u) - 127;
                    pend = __uint_as_float((uint)(127 - kap) << 23);
                    pk   = kap;
                    vml  = gmx;
                }
                const int nb = buf ^ 1;

                // exp(em) for this step, from registers loaded a group ago:
                // independent of acc/bfr -> scheduled under MFMA shadow.
                float ex_[2][4];
                #pragma unroll
                for (int t = 0; t < 2; ++t)
                    #pragma unroll
                    for (int r = 0; r < 4; ++r)
                        ex_[t][r] = exp2f(exv[u][t][r] * LOG2E);

                // B fragments, then the MFMA block
                bf16x8 bfr[8];
                #pragma unroll
                for (int kt = 0; kt < 8; ++kt)
                    bfr[kt] = *reinterpret_cast<const bf16x8*>(&Al[buf][l][kt * 32 + q * 8]);

                // 4 independent chains (2 m-tiles x even/odd kt), depth 4
                f32x4 ac[2][2] = {{f32x4{0,0,0,0}, f32x4{0,0,0,0}},
                                  {f32x4{0,0,0,0}, f32x4{0,0,0,0}}};
                #pragma unroll
                for (int kt = 0; kt < 8; ++kt) {
                    #pragma unroll
                    for (int t = 0; t < 2; ++t)
                        ac[t][kt & 1] = __builtin_amdgcn_mfma_f32_16x16x32_bf16(Afr[t][kt], bfr[kt], ac[t][kt & 1], 0, 0, 0);
                }
                f32x4 acc[2];
                #pragma unroll
                for (int t = 0; t < 2; ++t) acc[t] = ac[t][0] + ac[t][1];

                const int mk = mks[u];
                float v[2][4];

                #pragma unroll
                for (int t = 0; t < 2; ++t) {
                    if (DIR == 0) {
                        #pragma unroll
                        for (int r = 0; r < 4; ++r)
                            v[t][r] = acc[t][r] * ex_[t][r] * pend;
                    } else {
                        #pragma unroll
                        for (int r = 0; r < 4; ++r) {
                            float g  = acc[t][r] * pend;
                            float sv = mk ? g : areg[t][r];
                            areg[t][r] = sv;
                            v[t][r] = sv * ex_[t][r];
                        }
                    }
                }

                // LDS write of the new stored vector
                if (DIR == 0) {
                    if (mk) {
                        #pragma unroll
                        for (int t = 0; t < 2; ++t) {
                            int j0 = w * 32 + t * 16 + q * 4;
                            uint2 wv;
                            wv.x = pack_bf16x2(v[t][0], v[t][1]);
                            wv.y = pack_bf16x2(v[t][2], v[t][3]);
                            *reinterpret_cast<uint2*>(&Al[nb][l][j0]) = wv;
                        }
                    } else {
                        #pragma unroll
                        for (int t = 0; t < 2; ++t) {
                            int j0 = w * 32 + t * 16 + q * 4;
                            *reinterpret_cast<uint2*>(&Al[nb][l][j0]) =
                                *reinterpret_cast<const uint2*>(&Al[buf][l][j0]);
                        }
                    }
                } else {
                    #pragma unroll
                    for (int t = 0; t < 2; ++t) {
                        int j0 = w * 32 + t * 16 + q * 4;
                        uint2 wv;
                        wv.x = pack_bf16x2(v[t][0], v[t][1]);
                        wv.y = pack_bf16x2(v[t][2], v[t][3]);
                        *reinterpret_cast<uint2*>(&Al[nb][l][j0]) = wv;
                    }
                }

                // per-step max tracking only where needed (fwd score chain)
                if (track) {
                    float lmx = vmax24(v);
                    vml = mk ? lmx : vml;
                }
                ls  += mk ? pk : 0;
                pend = mk ? 1.0f : pend;
                pk   = mk ? 0 : pk;

                const bool rn = (u == 3) || (idx == NSTEP - 1);
                if (rn) {   // publish stored-vector max for next renorm group
                    float fm = track ? vml : vmax24(v);
                    fm = fmaxf(fm, __shfl_xor(fm, 16));
                    fm = fmaxf(fm, __shfl_xor(fm, 32));
                    if (q == 0) mx2[l][w] = fm;
                }

                wg_barrier();
                buf = nb;
            }
        }

        #pragma unroll
        for (int u = 0; u < 4; ++u) {
            #pragma unroll
            for (int t = 0; t < 2; ++t) exv[u][t] = exn[u][t];
            mks[u] = mkn[u];
        }
    }

    // ---- write mid vector + exponent to workspace
    const int cidx = scan * 2 + DIR;
    if (DIR) {
        // areg holds raw G_{H+1} (scaled), f32
        #pragma unroll
        for (int t = 0; t < 2; ++t) {
            int j0 = w * 32 + t * 16 + q * 4;
            f32x4 o = {areg[t][0], areg[t][1], areg[t][2], areg[t][3]};
            *reinterpret_cast<f32x4*>(&vecbuf[((size_t)cidx * B + b) * T + j0]) = o;
        }
    } else {
        // stored alpha_H (scaled), bf16 in LDS
        #pragma unroll
        for (int t = 0; t < 2; ++t) {
            int j0 = w * 32 + t * 16 + q * 4;
            uint2 wv = *reinterpret_cast<const uint2*>(&Al[buf][l][j0]);
            f32x4 o = {bf2f((ushort)(wv.x & 0xFFFF)), bf2f((ushort)(wv.x >> 16)),
                       bf2f((ushort)(wv.y & 0xFFFF)), bf2f((ushort)(wv.y >> 16))};
            *reinterpret_cast<f32x4*>(&vecbuf[((size_t)cidx * B + b) * T + j0]) = o;
        }
    }
    if (w == 0 && q == 0) lsbuf[cidx * B + b] = ls;

    #undef EROW
    #undef MROW
}

__launch_bounds__(512, 2)
__global__ void crf_scan(const float* __restrict__ em,
                         const int* __restrict__ mask,
                         const float* __restrict__ startt,
                         const float* __restrict__ endt,
                         const ushort* __restrict__ Et,     // fwd A
                         const ushort* __restrict__ Emat,   // bwd A
                         float* __restrict__ vecbuf,
                         int* __restrict__ lsbuf,
                         int* __restrict__ cnt,
                         float* __restrict__ out)
{
    __shared__ __align__(16) ushort Al[2][16][LDP];
    __shared__ __align__(16) float mx2[16][8];
    __shared__ __align__(16) float red[2][4][B];   // combine reduction
    __shared__ int lastdone;

    const int scan = blockIdx.x & 1;
    const int dir  = (blockIdx.x >> 1) & 1;
    const int bg   = blockIdx.x >> 2;

    if (dir == 0)
        scan_body<0>(em, mask, startt, endt, Et,   vecbuf, lsbuf, scan, bg, Al, mx2);
    else
        scan_body<1>(em, mask, startt, endt, Emat, vecbuf, lsbuf, scan, bg, Al, mx2);

    // ---- last-WG-done: the final WG to finish runs the combine.
    // res[scan][b] = ls_f + ls_b + log2(dot(alpha_H, G_{H+1}));
    // out[b] = (partition - score) * ln2
    __threadfence();                       // release our vec/lsbuf writes
    __syncthreads();
    if (threadIdx.x == 0)
        lastdone = (atomicAdd(cnt, 1) == NWG - 1);
    __syncthreads();
    if (!lastdone) return;
    __threadfence();                       // acquire other WGs' writes

    const int part = threadIdx.x >> 7;     // 0..3 (64-wide j chunk)
    const int bb   = threadIdx.x & 127;    // batch
    float d[2];
    #pragma unroll
    for (int c = 0; c < 2; ++c) {          // c: 0=partition, 1=score
        const float* vf = vecbuf + ((size_t)(c * 2 + 0) * B + bb) * T + part * 64;
        const float* vb = vecbuf + ((size_t)(c * 2 + 1) * B + bb) * T + part * 64;
        float s = 0.0f;
        #pragma unroll
        for (int k = 0; k < 64; k += 4) {
            f32x4 a = *reinterpret_cast<const f32x4*>(&vf[k]);
            f32x4 g = *reinterpret_cast<const f32x4*>(&vb[k]);
            s += a[0] * g[0] + a[1] * g[1] + a[2] * g[2] + a[3] * g[3];
        }
        d[c] = s;
    }
    red[0][part][bb] = d[0];
    red[1][part][bb] = d[1];
    __syncthreads();
    if (part == 0) {
        float d0 = (red[0][0][bb] + red[0][1][bb]) + (red[0][2][bb] + red[0][3][bb]);
        float d1 = (red[1][0][bb] + red[1][1][bb]) + (red[1][2][bb] + red[1][3][bb]);
        float r0 = (float)(lsbuf[0 * B + bb] + lsbuf[1 * B + bb]) + log2f(d0);
        float r1 = (float)(lsbuf[2 * B + bb] + lsbuf[3 * B + bb]) + log2f(d1);
        out[bb] = (r0 - r1) * LN2;
    }
}

extern "C" void kernel_launch(void* const* d_in, const int* in_sizes, int n_in,
                              void* d_out, int out_size, void* d_ws, size_t ws_size,
                              hipStream_t stream) {
    (void)in_sizes; (void)n_in; (void)out_size; (void)ws_size;
    const float* em = (const float*)d_in[0];
    const int*   mk = (const int*)d_in[1];
    const float* st = (const float*)d_in[2];
    const float* en = (const float*)d_in[3];
    const float* tr = (const float*)d_in[4];

    const size_t mat_bytes = (size_t)T * T * sizeof(ushort);       // 128 KiB
    const size_t vec_bytes = (size_t)4 * B * T * sizeof(float);    // 512 KiB
    const size_t ls_bytes  = (size_t)4 * B * sizeof(int);          // 2 KiB

    char* wp = (char*)d_ws;
    ushort* Et  = (ushort*)wp; wp += mat_bytes;
    ushort* Em  = (ushort*)wp; wp += mat_bytes;
    float*  vec = (float*)wp;  wp += vec_bytes;
    int*    lsb = (int*)wp;    wp += ls_bytes;
    int*    cnt = (int*)wp;

    prep_mats<<<T, T, 0, stream>>>(tr, Et, Em, cnt);
    crf_scan<<<NWG, 512, 0, stream>>>(em, mk, st, en, Et, Em, vec, lsb, cnt, (float*)d_out);
}

// Round 11
// 346.097 us; speedup vs baseline: 1.0591x; 1.0591x over previous
//
#include <hip/hip_runtime.h>
#include <hip/hip_bf16.h>
#include <stdint.h>

#define LOG2E 1.44269504088896340736f
#define LN2   0.69314718055994530942f

typedef __attribute__((ext_vector_type(8))) __bf16 bf16x8;
typedef __attribute__((ext_vector_type(4))) float  f32x4;

static constexpr int B = 128, S = 512, T = 256;
static constexpr int LDP = T + 8;   // padded LDS row (bf16 elems)
static constexpr int H   = 256;     // forward covers s=1..H, backward s=S-1..H+1
static constexpr int NSF = H;           // 256 forward steps
static constexpr int NSB = S - 1 - H;   // 255 backward steps

static __device__ __forceinline__ uint pack_bf16x2(float a, float b) {
    __hip_bfloat162 h = __float22bfloat162_rn(make_float2(a, b));
    union { __hip_bfloat162 h; uint u; } cv; cv.h = h;
    return cv.u;
}
static __device__ __forceinline__ float bf2f(ushort u) {
    return __uint_as_float(((uint)u) << 16);
}

// lgkm-only barrier: LDS writes must be visible, but leave global loads in
// flight (no vmcnt drain).  sched_barrier stops motion across it (rule #18).
static __device__ __forceinline__ void wg_barrier() {
    asm volatile("s_waitcnt lgkmcnt(0)" ::: "memory");
    __builtin_amdgcn_s_barrier();
    __builtin_amdgcn_sched_barrier(0);
}

// fmax over the 2x4 epilogue tile in a FIXED order so the tracking path and
// the rn-only path produce bitwise-equal maxima.
static __device__ __forceinline__ float vmax24(const float v[2][4]) {
    float m = 0.0f;
    #pragma unroll
    for (int t = 0; t < 2; ++t)
        #pragma unroll
        for (int r = 0; r < 4; ++r) m = fmaxf(m, v[t][r]);
    return m;
}

// ---- prep: Et[j][i] = bf16(exp(trans[i][j])), Em[i][j] = bf16(exp(trans[i][j]))
__global__ void prep_mats(const float* __restrict__ trans,
                          ushort* __restrict__ Et, ushort* __restrict__ Em) {
    int i = blockIdx.x;    // 256 (row of trans)
    int j = threadIdx.x;   // 256
    float e = exp2f(trans[i * T + j] * LOG2E);
    uint u = __float_as_uint(e);
    ushort h = (ushort)((u + 0x7FFFu + ((u >> 16) & 1u)) >> 16);  // RTNE
    Em[i * T + j] = h;     // exp(trans) row-major   (backward A-operand)
    Et[j * T + i] = h;     // exp(trans) transposed  (forward  A-operand)
}

// ---- scan body: 8 waves per WG (512 thr), wave w owns j in [32w, 32w+32).
// Measured-best structure (1.02 us/step): straight k-tile order, 2-way
// accumulator split, lgkm-only barrier, em read as f32 with one-group-ahead
// prefetch and exp2f computed before the MFMA block (rides in pipe shadows).
template<int DIR>
static __device__ __forceinline__ void scan_body(
    const float* __restrict__ em,
    const int* __restrict__ mask, const float* __restrict__ startt,
    const float* __restrict__ endt, const ushort* __restrict__ Amat,
    float* __restrict__ vecbuf, int* __restrict__ lsbuf,
    const int scan, const int bg,
    ushort (&Al)[2][16][LDP], float (&mx2)[16][8])
{
    constexpr int NSTEP = DIR ? NSB : NSF;
    constexpr int PGRP  = (NSTEP + 3) / 4;

    const int tid  = threadIdx.x;
    const int w    = tid >> 6;          // wave 0..7
    const int lane = tid & 63;
    const int q    = lane >> 4;         // quad 0..3
    const int l    = lane & 15;         // local batch 0..15
    const int b    = bg * 16 + l;

    // step idx -> em row (epilogue) / mask row (the where())
    #define EROW(ix) (DIR ? (S - 2 - (ix)) : (1 + (ix)))
    #define MROW(ix) (DIR ? (S - 1 - (ix)) : (1 + (ix)))

    // ---- A fragments (step-invariant): 64 VGPRs/wave
    bf16x8 Afr[2][8];
    #pragma unroll
    for (int t = 0; t < 2; ++t) {
        int j = w * 32 + t * 16 + l;
        #pragma unroll
        for (int kt = 0; kt < 8; ++kt)
            Afr[t][kt] = *reinterpret_cast<const bf16x8*>(&Amat[j * T + kt * 32 + q * 8]);
    }

    const float* emrow = em  + (size_t)b * S * T;
    const int*   mrow  = mask + (size_t)b * S;

    int ls = 0;
    int buf = 0;
    float areg[2][4];   // DIR=1: raw beta (pre-em), scaled. DIR=0: unused.

    // ---- init
    {
        const int    r0 = DIR ? (S - 1) : 0;
        const float* tv = DIR ? endt : startt;
        float v0[2][4], gg[2][4]; float mx = 0.0f;
        #pragma unroll
        for (int t = 0; t < 2; ++t) {
            int j0 = w * 32 + t * 16 + q * 4;
            f32x4 e4 = *reinterpret_cast<const f32x4*>(&emrow[(size_t)r0 * T + j0]);
            f32x4 s4 = *reinterpret_cast<const f32x4*>(&tv[j0]);
            #pragma unroll
            for (int r = 0; r < 4; ++r) {
                float full = exp2f((e4[r] + s4[r]) * LOG2E);
                v0[t][r] = full;
                gg[t][r] = DIR ? exp2f(s4[r] * LOG2E) : full;
                mx = fmaxf(mx, full);
            }
        }
        mx = fmaxf(mx, __shfl_xor(mx, 16));
        mx = fmaxf(mx, __shfl_xor(mx, 32));
        if (q == 0) mx2[l][w] = mx;
        __syncthreads();
        f32x4 ma = *reinterpret_cast<const f32x4*>(&mx2[l][0]);
        f32x4 mb = *reinterpret_cast<const f32x4*>(&mx2[l][4]);
        float gmx = fmaxf(fmaxf(fmaxf(ma[0], ma[1]), fmaxf(ma[2], ma[3])),
                          fmaxf(fmaxf(mb[0], mb[1]), fmaxf(mb[2], mb[3])));
        int e = (int)((__float_as_uint(gmx) >> 23) & 255u) - 127;
        float sc = __uint_as_float((uint)(127 - e) << 23);   // exact 2^-e
        ls = e;
        #pragma unroll
        for (int t = 0; t < 2; ++t) {
            int j0 = w * 32 + t * 16 + q * 4;
            uint2 wv;
            wv.x = pack_bf16x2(v0[t][0] * sc, v0[t][1] * sc);
            wv.y = pack_bf16x2(v0[t][2] * sc, v0[t][3] * sc);
            *reinterpret_cast<uint2*>(&Al[0][l][j0]) = wv;
            if (DIR) {
                #pragma unroll
                for (int r = 0; r < 4; ++r) areg[t][r] = gg[t][r] * sc;
            }
        }
        __syncthreads();
        if (q == 0) mx2[l][w] = mx * sc;
        __syncthreads();
    }

    // full per-step max tracking only needed when the stored vector can
    // persist across a masked step: forward score chain only.
    const bool track = (DIR == 0) && (scan != 0);

    // ---- preload em/mask for group 0 (idx 0..3), f32
    f32x4 exv[4][2]; int mks[4];
    #pragma unroll
    for (int u = 0; u < 4; ++u) {
        int iu = u < NSTEP ? u : NSTEP - 1;
        #pragma unroll
        for (int t = 0; t < 2; ++t) {
            int j0 = w * 32 + t * 16 + q * 4;
            exv[u][t] = *reinterpret_cast<const f32x4*>(&emrow[(size_t)EROW(iu) * T + j0]);
        }
        mks[u] = (scan && u < NSTEP) ? mrow[MROW(iu)] : 1;
    }

    for (int p = 0; p < PGRP; ++p) {
        // ---- issue next group's loads now (stay in flight across barriers)
        f32x4 exn[4][2]; int mkn[4];
        #pragma unroll
        for (int u = 0; u < 4; ++u) {
            int idx  = 4 * (p + 1) + u;
            int idxc = idx < NSTEP ? idx : NSTEP - 1;
            #pragma unroll
            for (int t = 0; t < 2; ++t) {
                int j0 = w * 32 + t * 16 + q * 4;
                exn[u][t] = *reinterpret_cast<const f32x4*>(&emrow[(size_t)EROW(idxc) * T + j0]);
            }
            mkn[u] = (scan && idx < NSTEP) ? mrow[MROW(idxc)] : 1;
        }

        float pend = 1.0f, vml = 0.0f; int pk = 0;

        #pragma unroll
        for (int u = 0; u < 4; ++u) {
            const int idx = 4 * p + u;
            if (idx < NSTEP) {
                if (u == 0) {   // renorm-group start: derive kappa
                    f32x4 ma = *reinterpret_cast<const f32x4*>(&mx2[l][0]);
                    f32x4 mb = *reinterpret_cast<const f32x4*>(&mx2[l][4]);
                    float gmx = fmaxf(fmaxf(fmaxf(ma[0], ma[1]), fmaxf(ma[2], ma[3])),
                                      fmaxf(fmaxf(mb[0], mb[1]), fmaxf(mb[2], mb[3])));
                    int kap = (int)((__float_as_uint(gmx) >> 23) & 255u) - 127;
                    pend = __uint_as_float((uint)(127 - kap) << 23);
                    pk   = kap;
                    vml  = gmx;
                }
                const int nb = buf ^ 1;

                // exp(em) for this step, from registers loaded a group ago:
                // independent of acc/bfr -> scheduled under MFMA shadow.
                float ex_[2][4];
                #pragma unroll
                for (int t = 0; t < 2; ++t)
                    #pragma unroll
                    for (int r = 0; r < 4; ++r)
                        ex_[t][r] = exp2f(exv[u][t][r] * LOG2E);

                // B fragments, then the MFMA block
                bf16x8 bfr[8];
                #pragma unroll
                for (int kt = 0; kt < 8; ++kt)
                    bfr[kt] = *reinterpret_cast<const bf16x8*>(&Al[buf][l][kt * 32 + q * 8]);

                // 4 independent chains (2 m-tiles x even/odd kt), depth 4
                f32x4 ac[2][2] = {{f32x4{0,0,0,0}, f32x4{0,0,0,0}},
                                  {f32x4{0,0,0,0}, f32x4{0,0,0,0}}};
                #pragma unroll
                for (int kt = 0; kt < 8; ++kt) {
                    #pragma unroll
                    for (int t = 0; t < 2; ++t)
                        ac[t][kt & 1] = __builtin_amdgcn_mfma_f32_16x16x32_bf16(Afr[t][kt], bfr[kt], ac[t][kt & 1], 0, 0, 0);
                }
                f32x4 acc[2];
                #pragma unroll
                for (int t = 0; t < 2; ++t) acc[t] = ac[t][0] + ac[t][1];

                const int mk = mks[u];
                float v[2][4];

                #pragma unroll
                for (int t = 0; t < 2; ++t) {
                    if (DIR == 0) {
                        #pragma unroll
                        for (int r = 0; r < 4; ++r)
                            v[t][r] = acc[t][r] * ex_[t][r] * pend;
                    } else {
                        #pragma unroll
                        for (int r = 0; r < 4; ++r) {
                            float g  = acc[t][r] * pend;
                            float sv = mk ? g : areg[t][r];
                            areg[t][r] = sv;
                            v[t][r] = sv * ex_[t][r];
                        }
                    }
                }

                // LDS write of the new stored vector
                if (DIR == 0) {
                    if (mk) {
                        #pragma unroll
                        for (int t = 0; t < 2; ++t) {
                            int j0 = w * 32 + t * 16 + q * 4;
                            uint2 wv;
                            wv.x = pack_bf16x2(v[t][0], v[t][1]);
                            wv.y = pack_bf16x2(v[t][2], v[t][3]);
                            *reinterpret_cast<uint2*>(&Al[nb][l][j0]) = wv;
                        }
                    } else {
                        #pragma unroll
                        for (int t = 0; t < 2; ++t) {
                            int j0 = w * 32 + t * 16 + q * 4;
                            *reinterpret_cast<uint2*>(&Al[nb][l][j0]) =
                                *reinterpret_cast<const uint2*>(&Al[buf][l][j0]);
                        }
                    }
                } else {
                    #pragma unroll
                    for (int t = 0; t < 2; ++t) {
                        int j0 = w * 32 + t * 16 + q * 4;
                        uint2 wv;
                        wv.x = pack_bf16x2(v[t][0], v[t][1]);
                        wv.y = pack_bf16x2(v[t][2], v[t][3]);
                        *reinterpret_cast<uint2*>(&Al[nb][l][j0]) = wv;
                    }
                }

                // per-step max tracking only where needed (fwd score chain)
                if (track) {
                    float lmx = vmax24(v);
                    vml = mk ? lmx : vml;
                }
                ls  += mk ? pk : 0;
                pend = mk ? 1.0f : pend;
                pk   = mk ? 0 : pk;

                const bool rn = (u == 3) || (idx == NSTEP - 1);
                if (rn) {   // publish stored-vector max for next renorm group
                    float fm = track ? vml : vmax24(v);
                    fm = fmaxf(fm, __shfl_xor(fm, 16));
                    fm = fmaxf(fm, __shfl_xor(fm, 32));
                    if (q == 0) mx2[l][w] = fm;
                }

                wg_barrier();
                buf = nb;
            }
        }

        #pragma unroll
        for (int u = 0; u < 4; ++u) {
            #pragma unroll
            for (int t = 0; t < 2; ++t) exv[u][t] = exn[u][t];
            mks[u] = mkn[u];
        }
    }

    // ---- write mid vector + exponent to workspace
    const int cidx = scan * 2 + DIR;
    if (DIR) {
        // areg holds raw G_{H+1} (scaled), f32
        #pragma unroll
        for (int t = 0; t < 2; ++t) {
            int j0 = w * 32 + t * 16 + q * 4;
            f32x4 o = {areg[t][0], areg[t][1], areg[t][2], areg[t][3]};
            *reinterpret_cast<f32x4*>(&vecbuf[((size_t)cidx * B + b) * T + j0]) = o;
        }
    } else {
        // stored alpha_H (scaled), bf16 in LDS
        #pragma unroll
        for (int t = 0; t < 2; ++t) {
            int j0 = w * 32 + t * 16 + q * 4;
            uint2 wv = *reinterpret_cast<const uint2*>(&Al[buf][l][j0]);
            f32x4 o = {bf2f((ushort)(wv.x & 0xFFFF)), bf2f((ushort)(wv.x >> 16)),
                       bf2f((ushort)(wv.y & 0xFFFF)), bf2f((ushort)(wv.y >> 16))};
            *reinterpret_cast<f32x4*>(&vecbuf[((size_t)cidx * B + b) * T + j0]) = o;
        }
    }
    if (w == 0 && q == 0) lsbuf[cidx * B + b] = ls;

    #undef EROW
    #undef MROW
}

__launch_bounds__(512, 2)
__global__ void crf_scan(const float* __restrict__ em,
                         const int* __restrict__ mask,
                         const float* __restrict__ startt,
                         const float* __restrict__ endt,
                         const ushort* __restrict__ Et,     // fwd A
                         const ushort* __restrict__ Emat,   // bwd A
                         float* __restrict__ vecbuf,
                         int* __restrict__ lsbuf)
{
    __shared__ __align__(16) ushort Al[2][16][LDP];
    __shared__ __align__(16) float mx2[16][8];

    const int scan = blockIdx.x & 1;
    const int dir  = (blockIdx.x >> 1) & 1;
    const int bg   = blockIdx.x >> 2;

    if (dir == 0)
        scan_body<0>(em, mask, startt, endt, Et,   vecbuf, lsbuf, scan, bg, Al, mx2);
    else
        scan_body<1>(em, mask, startt, endt, Emat, vecbuf, lsbuf, scan, bg, Al, mx2);
}

// ---- combine: one block per batch b; 256 threads reduce both scans' dots.
// res[scan][b] = ls_f + ls_b + log2(dot(alpha_H, G_{H+1}));
// out[b] = (partition - score) * ln2
__global__ void combine2(const float* __restrict__ vecbuf, const int* __restrict__ lsbuf,
                         float* __restrict__ out) {
    const int b = blockIdx.x;       // 128
    const int j = threadIdx.x;      // 256
    const float* vf0 = vecbuf + ((size_t)0 * B + b) * T;
    const float* vb0 = vecbuf + ((size_t)1 * B + b) * T;
    const float* vf1 = vecbuf + ((size_t)2 * B + b) * T;
    const float* vb1 = vecbuf + ((size_t)3 * B + b) * T;
    float p0 = vf0[j] * vb0[j];
    float p1 = vf1[j] * vb1[j];
    // wave reduce (identical op order for both scans)
    #pragma unroll
    for (int off = 32; off >= 1; off >>= 1) {
        p0 += __shfl_xor(p0, off);
        p1 += __shfl_xor(p1, off);
    }
    __shared__ float s0[4], s1[4];
    const int wv = j >> 6, ln = j & 63;
    if (ln == 0) { s0[wv] = p0; s1[wv] = p1; }
    __syncthreads();
    if (j == 0) {
        float d0 = (s0[0] + s0[1]) + (s0[2] + s0[3]);
        float d1 = (s1[0] + s1[1]) + (s1[2] + s1[3]);
        float r0 = (float)(lsbuf[0 * B + b] + lsbuf[1 * B + b]) + log2f(d0);
        float r1 = (float)(lsbuf[2 * B + b] + lsbuf[3 * B + b]) + log2f(d1);
        out[b] = (r0 - r1) * LN2;
    }
}

extern "C" void kernel_launch(void* const* d_in, const int* in_sizes, int n_in,
                              void* d_out, int out_size, void* d_ws, size_t ws_size,
                              hipStream_t stream) {
    (void)in_sizes; (void)n_in; (void)out_size; (void)ws_size;
    const float* em = (const float*)d_in[0];
    const int*   mk = (const int*)d_in[1];
    const float* st = (const float*)d_in[2];
    const float* en = (const float*)d_in[3];
    const float* tr = (const float*)d_in[4];

    const size_t mat_bytes = (size_t)T * T * sizeof(ushort);       // 128 KiB
    const size_t vec_bytes = (size_t)4 * B * T * sizeof(float);    // 512 KiB

    char* wp = (char*)d_ws;
    ushort* Et = (ushort*)wp; wp += mat_bytes;
    ushort* Em = (ushort*)wp; wp += mat_bytes;
    float*  vec = (float*)wp; wp += vec_bytes;
    int*    lsb = (int*)wp;

    prep_mats<<<T, T, 0, stream>>>(tr, Et, Em);
    crf_scan<<<32, 512, 0, stream>>>(em, mk, st, en, Et, Em, vec, lsb);
    combine2<<<B, 256, 0, stream>>>(vec, lsb, (float*)d_out);
}